// Round 1
// 919.259 us; speedup vs baseline: 1.1054x; 1.1054x over previous
//
#include <hip/hip_runtime.h>

#define TSZ (1u << 19)
#define HPRIME 2654435761u

typedef short bf16x8 __attribute__((ext_vector_type(8)));
typedef float f32x4 __attribute__((ext_vector_type(4)));

__device__ __forceinline__ float sigmoidf(float x) {
    return 1.0f / (1.0f + __expf(-x));
}

__device__ __forceinline__ unsigned short f2b(float f) {
    union { float f; unsigned u; } v; v.f = f;
    return (unsigned short)((v.u + 0x7FFFu + ((v.u >> 16) & 1u)) >> 16);
}

__device__ __forceinline__ unsigned f2b_pack(float a, float b) {
    union { float f; unsigned u; } x, y; x.f = a; y.f = b;
    unsigned ra = (x.u + 0x7FFFu + ((x.u >> 16) & 1u)) >> 16;
    unsigned rb = (y.u + 0x7FFFu + ((y.u >> 16) & 1u)) & 0xFFFF0000u;
    return ra | rb;
}

// Precompute B-operand MFMA fragments (bf16) for Wp2 (64x64) and W_tiny cols
// 1..64 (32x64). B layout for mfma_f32_16x16x32_bf16: lane holds
// B[k = (lane>>4)*8 + j][n = lane&15], j=0..7 contiguous in the 8-vector.
__global__ void repack_frags(const float* __restrict__ Wp2,
                             const float* __restrict__ Wt,
                             unsigned short* __restrict__ wp2F,
                             unsigned short* __restrict__ wtF) {
    int t = blockIdx.x * blockDim.x + threadIdx.x;
    if (t < 4096) {  // 8 frags (kstep*4+ntile) x 64 lanes x 8
        int j = t & 7, lane = (t >> 3) & 63, f = t >> 9;
        int ks = f >> 2, nt = f & 3;
        int k = ks * 32 + (lane >> 4) * 8 + j;
        int n = nt * 16 + (lane & 15);
        wp2F[t] = f2b(Wp2[k * 64 + n]);
    }
    if (t < 2048) {  // 4 frags (ntile) x 64 lanes x 8, K=32
        int j = t & 7, lane = (t >> 3) & 63, nt = t >> 9;
        int k = (lane >> 4) * 8 + j;
        int n = nt * 16 + (lane & 15);
        wtF[t] = f2b(Wt[k * 65 + 1 + n]);
    }
}

// Barrier-free version: every LDS structure is wave-private (Abuf region,
// featBuf overlay, sPrior slice), and DS ops execute in-order within a wave,
// so no __syncthreads() is needed anywhere. Dropping the sOut staging buffer
// (direct global stores from MFMA accumulators; 64B-segment coalescing) cuts
// LDS from 54784 -> 37888 B: 2 -> 4 blocks/CU (8 -> 16 waves/CU), which is
// the latency-hiding the 64 scattered table gathers per point need.
__global__ __launch_bounds__(256, 4)
void sdf_main(const float* __restrict__ in,
              const float* __restrict__ tables,
              const float* __restrict__ Wp1,
              const float* __restrict__ Wp3,
              const float* __restrict__ bt,
              const float* __restrict__ Wt,
              const unsigned short* __restrict__ wp2F,
              const unsigned short* __restrict__ wtF,
              float* __restrict__ out, int N)
{
    // Per-wave A-staging buffer, stride 72 bf16 (144 B: 16B-aligned rows, ~2-way
    // banks on b128 frag reads). featBuf (stride 40) overlays the SAME wave's
    // region (wave-private, in-order DS ops -> no cross-wave hazard).
    __shared__ unsigned short Abuf[4 * 64 * 72];  // 36864 B
    __shared__ float sPrior[256];                 // 1024 B
    // total 37888 B -> 4 blocks/CU

    const int tid = threadIdx.x;
    const int wave = tid >> 6, lane = tid & 63;
    const int quad = lane >> 4, col = lane & 15;
    const long long n0 = (long long)blockIdx.x * 256;
    const int n = (int)n0 + tid;
    const int nc = n < N ? n : N - 1;

    const float px = in[nc * 3 + 0];
    const float py = in[nc * 3 + 1];
    const float pz = in[nc * 3 + 2];

    // ---------------- frequency encoding ----------------
    const float PIF = 3.14159274101257324e+00f;
    float e[12];
    e[0] = __sinf(px * PIF); e[1]  = __sinf(px * (2.0f * PIF)); e[2]  = __sinf(px * (4.0f * PIF));
    e[3] = __cosf(px * PIF); e[4]  = __cosf(px * (2.0f * PIF)); e[5]  = __cosf(px * (4.0f * PIF));
    e[6] = __sinf(py * PIF); e[7]  = __sinf(py * (2.0f * PIF)); e[8]  = __sinf(py * (4.0f * PIF));
    e[9] = __cosf(py * PIF); e[10] = __cosf(py * (2.0f * PIF)); e[11] = __cosf(py * (4.0f * PIF));

    // ---------------- layer1 (VALU, 768 FMA) -> h bf16 into Abuf A-layout ------
    unsigned short* myA = Abuf + wave * 64 * 72 + lane * 72;
#pragma unroll
    for (int j4 = 0; j4 < 64; j4 += 4) {
        float s0 = 0.f, s1 = 0.f, s2 = 0.f, s3 = 0.f;
#pragma unroll
        for (int k = 0; k < 12; k++) {
            const float4 w = *(const float4*)(Wp1 + k * 64 + j4);
            s0 += e[k] * w.x; s1 += e[k] * w.y; s2 += e[k] * w.z; s3 += e[k] * w.w;
        }
        uint2 pk;
        pk.x = f2b_pack(sigmoidf(s0), sigmoidf(s1));
        pk.y = f2b_pack(sigmoidf(s2), sigmoidf(s3));
        *reinterpret_cast<uint2*>(myA + j4) = pk;
    }
    // no barrier: Abuf region is wave-private; DS ops in-order within a wave

    // ---------------- layer2 via MFMA (M=64 pts, K=64, N=64) + prior reduce ----
    bf16x8 bfr[8];
#pragma unroll
    for (int f = 0; f < 8; f++)
        bfr[f] = *reinterpret_cast<const bf16x8*>(wp2F + (f * 64 + lane) * 8);
    float w3[4];
#pragma unroll
    for (int nt = 0; nt < 4; nt++) w3[nt] = Wp3[nt * 16 + col];

#pragma unroll
    for (int mt = 0; mt < 4; mt++) {
        const unsigned short* ar = Abuf + wave * 4608 + (mt * 16 + col) * 72;
        const bf16x8 a0 = *reinterpret_cast<const bf16x8*>(ar + quad * 8);
        const bf16x8 a1 = *reinterpret_cast<const bf16x8*>(ar + 32 + quad * 8);
        float pp[4] = {0.f, 0.f, 0.f, 0.f};
#pragma unroll
        for (int nt = 0; nt < 4; nt++) {
            f32x4 acc = {0.f, 0.f, 0.f, 0.f};
            acc = __builtin_amdgcn_mfma_f32_16x16x32_bf16(a0, bfr[nt], acc, 0, 0, 0);
            acc = __builtin_amdgcn_mfma_f32_16x16x32_bf16(a1, bfr[4 + nt], acc, 0, 0, 0);
#pragma unroll
            for (int r = 0; r < 4; r++)
                pp[r] += w3[nt] * sigmoidf(acc[r]);
        }
#pragma unroll
        for (int r = 0; r < 4; r++) {   // sum over the 16 cols of the group
            pp[r] += __shfl_xor(pp[r], 1, 64);
            pp[r] += __shfl_xor(pp[r], 2, 64);
            pp[r] += __shfl_xor(pp[r], 4, 64);
            pp[r] += __shfl_xor(pp[r], 8, 64);
            if (col == r) sPrior[wave * 64 + mt * 16 + quad * 4 + r] = pp[r];
        }
    }

    // ---------------- hash gather (fp32) -> featBuf bf16 + x0 ------------------
    const float scl[16] = {15.f, 23.f, 35.f, 53.f, 80.f, 120.5f, 181.25f, 272.375f,
                           409.0625f, 614.09375f, 921.640625f, 1382.9609375f,
                           2074.94140625f, 3112.912109375f, 4669.8681640625f,
                           7005.30224609375f};
    const int ress[10] = {16, 24, 36, 54, 81, 122, 183, 274, 411, 616};
    const float cx = __fadd_rn(__fdiv_rn(px, 30.0f), 0.5f);
    const float cy = __fadd_rn(__fdiv_rn(py, 30.0f), 0.5f);

    unsigned short* myF = Abuf + wave * 4608 + lane * 40;  // overlay own wave's A region
    float x0 = bt[0];
    unsigned pk[4];
#pragma unroll
    for (int l = 0; l < 16; l++) {
        const float sc = scl[l];
        const float posx = __fadd_rn(__fmul_rn(cx, sc), 0.5f);
        const float posy = __fadd_rn(__fmul_rn(cy, sc), 0.5f);
        const float fx = floorf(posx), fy = floorf(posy);
        const float wx = __fsub_rn(posx, fx), wy = __fsub_rn(posy, fy);
        const int ix = (int)fx, iy = (int)fy;
        const float* tbl = tables + (size_t)l * (size_t)(TSZ * 2);
        int i00, i10, i01, i11;
        if (l < 10) {
            const int r = ress[l];
            i00 = ix + iy * r; i10 = i00 + 1; i01 = i00 + r; i11 = i01 + 1;
        } else {
            const unsigned ux = (unsigned)ix, uy = (unsigned)iy;
            const unsigned hy0 = uy * HPRIME, hy1 = (uy + 1u) * HPRIME;
            i00 = (int)((ux ^ hy0) & (TSZ - 1u));
            i10 = (int)(((ux + 1u) ^ hy0) & (TSZ - 1u));
            i01 = (int)((ux ^ hy1) & (TSZ - 1u));
            i11 = (int)(((ux + 1u) ^ hy1) & (TSZ - 1u));
        }
        const float2 q00 = *(const float2*)(tbl + 2 * i00);
        const float2 q10 = *(const float2*)(tbl + 2 * i10);
        const float2 q01 = *(const float2*)(tbl + 2 * i01);
        const float2 q11 = *(const float2*)(tbl + 2 * i11);
        const float omx = 1.0f - wx, omy = 1.0f - wy;
        const float f0 = (q00.x * omx + q10.x * wx) * omy + (q01.x * omx + q11.x * wx) * wy;
        const float f1 = (q00.y * omx + q10.y * wx) * omy + (q01.y * omx + q11.y * wx) * wy;
        x0 += f0 * Wt[(2 * l) * 65] + f1 * Wt[(2 * l + 1) * 65];
        pk[l & 3] = f2b_pack(f0, f1);
        if ((l & 3) == 3) {
            uint4 v; v.x = pk[0]; v.y = pk[1]; v.z = pk[2]; v.w = pk[3];
            *reinterpret_cast<uint4*>(myF + (l - 3) * 2) = v;
        }
    }
    // no barrier: featBuf + sPrior are wave-private, DS in-order within wave

    const float priorMe = sPrior[wave * 64 + lane];

    // ---------------- epilogue: W_tiny MFMA, direct global stores --------------
    // C/D layout per 16x16 tile: col = lane&15, row = quad*4 + r. For one store
    // instruction (fixed mt,nt,r) the wave writes 4 rows x 16 consecutive
    // dwords = 4 x 64B segments -- coalesced enough; L2 merges into full lines
    // (row-major walk over mt keeps the merge window tight).
    {
        bf16x8 fa[4];
#pragma unroll
        for (int mt = 0; mt < 4; mt++)
            fa[mt] = *reinterpret_cast<const bf16x8*>(
                Abuf + wave * 4608 + (mt * 16 + col) * 40 + quad * 8);
        bf16x8 wb[4];
        float bb[4];
#pragma unroll
        for (int nt = 0; nt < 4; nt++) {
            wb[nt] = *reinterpret_cast<const bf16x8*>(wtF + (nt * 64 + lane) * 8);
            bb[nt] = bt[1 + nt * 16 + col];
        }
        const long long wbase = n0 + (long long)wave * 64;
        float* op = out + (size_t)wbase * 65;
        const bool full = (wbase + 64 <= (long long)N);
#pragma unroll
        for (int mt = 0; mt < 4; mt++) {
#pragma unroll
            for (int nt = 0; nt < 4; nt++) {
                f32x4 acc = {0.f, 0.f, 0.f, 0.f};
                acc = __builtin_amdgcn_mfma_f32_16x16x32_bf16(fa[mt], wb[nt], acc, 0, 0, 0);
                if (full) {
#pragma unroll
                    for (int r = 0; r < 4; r++)
                        op[(mt * 16 + quad * 4 + r) * 65 + 1 + nt * 16 + col] = acc[r] + bb[nt];
                } else {
#pragma unroll
                    for (int r = 0; r < 4; r++) {
                        const int row = mt * 16 + quad * 4 + r;
                        if (wbase + row < (long long)N)
                            op[(size_t)row * 65 + 1 + nt * 16 + col] = acc[r] + bb[nt];
                    }
                }
            }
        }
        if (n < N) out[(size_t)n * 65] = pz - x0 - priorMe;
    }
}

extern "C" void kernel_launch(void* const* d_in, const int* in_sizes, int n_in,
                              void* d_out, int out_size, void* d_ws, size_t ws_size,
                              hipStream_t stream) {
    const float* inputs = (const float*)d_in[0];
    const float* tables = (const float*)d_in[1];
    const float* W_tiny = (const float*)d_in[2];
    const float* b_tiny = (const float*)d_in[3];
    const float* Wp1    = (const float*)d_in[4];
    const float* Wp2    = (const float*)d_in[5];
    const float* Wp3    = (const float*)d_in[6];
    float* out = (float*)d_out;
    unsigned short* wp2F = (unsigned short*)d_ws;        // 4096 bf16 = 8 KB
    unsigned short* wtF  = wp2F + 4096;                  // 2048 bf16 = 4 KB

    const int N = in_sizes[0] / 3;

    hipLaunchKernelGGL(repack_frags, dim3(16), dim3(256), 0, stream,
                       Wp2, W_tiny, wp2F, wtF);

    const int grid = (N + 255) / 256;
    hipLaunchKernelGGL(sdf_main, dim3(grid), dim3(256), 0, stream,
                       inputs, tables, Wp1, Wp3, b_tiny, W_tiny, wp2F, wtF, out, N);
}